// Round 14
// baseline (826.109 us; speedup 1.0000x reference)
//
#include <hip/hip_runtime.h>
#include <hip/hip_bf16.h>
#include <math.h>

#define NN 100000
#define NE 1600000
#define HID 128
#define NG 512
#define NB 512          // dst buckets
#define RB 196          // nodes per bucket (512*196 = 100352 >= NN)
#define PCHUNK 16384
#define NPARTB ((NE + PCHUNK - 1) / PCHUNK)   // 98
#define GEMM_GRID ((NN + 127) / 128)          // 782
#define GCHUNK 128
#define NCHUNKS ((NN + GCHUNK - 1) / GCHUNK)  // 782

typedef unsigned short ushort_t;
typedef __attribute__((ext_vector_type(8))) short bf16x8;
typedef __attribute__((ext_vector_type(8))) unsigned short ushort8_t;
typedef __attribute__((ext_vector_type(4))) float f32x4;

__device__ __forceinline__ ushort_t f2bf(float v) {
    unsigned u = __float_as_uint(v);
    unsigned r = (u + 0x7FFF + ((u >> 16) & 1)) >> 16;
    return (ushort_t)r;
}
__device__ __forceinline__ float bf2f(ushort_t u) {
    return __uint_as_float((unsigned)u << 16);
}

// PERM layout for h: node v, col k -> (v>>4)*2048 + (k>>3)*128 + (v&15)*8 + (k&7)

// ---------------- K1: per-block bucket histogram (no global atomics) + weight prep ----------------
__global__ __launch_bounds__(256) void hist_prepw(const int* __restrict__ ecol, int* __restrict__ bcount,
                                                  const float* __restrict__ lin1_w,
                                                  const float* __restrict__ gcn_w,
                                                  ushort_t* __restrict__ wt_hi,
                                                  ushort_t* __restrict__ wt_lo) {
    if (blockIdx.x < NPARTB) {
        __shared__ int lh[NB];
        const int blk = blockIdx.x, t = threadIdx.x;
        for (int i = t; i < NB; i += 256) lh[i] = 0;
        __syncthreads();
        const int e0 = blk * PCHUNK;
        const int e1 = min(e0 + PCHUNK, NE);
        for (int e = e0 + t; e < e1; e += 256) atomicAdd(&lh[ecol[e] / RB], 1);
        __syncthreads();
        for (int i = t; i < NB; i += 256) bcount[blk * NB + i] = lh[i];
    } else {
        int mb = blockIdx.x - NPARTB;
        int m = mb >> 3;
        int chunk = mb & 7;
        const float* W = (m == 0) ? lin1_w : gcn_w + (size_t)(m - 1) * 16384;
        ushort_t* hi = wt_hi + (size_t)m * 16384;
        ushort_t* lo = wt_lo + (size_t)m * 16384;
        for (int i = chunk * 2048 + threadIdx.x; i < (chunk + 1) * 2048; i += 256) {
            int j = i & 7;
            int lane = (i >> 3) & 63;
            int ks = (i >> 9) & 3;
            int ct = (i >> 11) & 7;
            int n = ct * 16 + (lane & 15);
            int k = ks * 32 + (lane >> 4) * 8 + j;
            float v = W[k * 128 + n];
            ushort_t h = f2bf(v);
            hi[i] = h;
            lo[i] = f2bf(v - bf2f(h));
        }
    }
}

// ---------------- K2: per-bucket block bases + bucket scan + invcnt ----------------
__global__ __launch_bounds__(NB) void scan_bases(const int* __restrict__ bcount, int* __restrict__ basew,
                                                 int* __restrict__ brp, int* __restrict__ rp,
                                                 const int* __restrict__ batch, float* __restrict__ invcnt) {
    __shared__ int s[NB];
    int t = threadIdx.x;
    int tot = 0;
    for (int k = 0; k < NPARTB; ++k) {
        int c = bcount[k * NB + t];
        basew[k * NB + t] = tot;
        tot += c;
    }
    s[t] = tot;
    __syncthreads();
    for (int off = 1; off < NB; off <<= 1) {
        int x = (t >= off) ? s[t - off] : 0;
        __syncthreads();
        s[t] += x;
        __syncthreads();
    }
    int ex = s[t] - tot;
    brp[t] = ex;
    if (t == NB - 1) { brp[NB] = s[t]; rp[NN] = s[t]; }

    int lo = 0, hi = NN;
    while (lo < hi) { int m = (lo + hi) >> 1; if (batch[m] < t) lo = m + 1; else hi = m; }
    int s0 = lo;
    lo = 0; hi = NN;
    while (lo < hi) { int m = (lo + hi) >> 1; if (batch[m] < t + 1) lo = m + 1; else hi = m; }
    int c = lo - s0;
    invcnt[t] = 1.0f / (float)(c > 0 ? c : 1);
}

// ---------------- GEMM body ----------------
template<bool F32A, int MODE>
__device__ __forceinline__ void gemm_body(int bid, int tid,
                                          const float* __restrict__ A,
                                          const ushort_t* __restrict__ a_bf,
                                          const ushort_t* __restrict__ wt_hi,
                                          const ushort_t* __restrict__ wt_lo,
                                          const float* __restrict__ bias,
                                          const float* __restrict__ dinv,
                                          ushort_t* __restrict__ out0,
                                          int N) {
    const int lane = tid & 63;
    const int wid = tid >> 6;
    const int rowBase = bid * 128 + wid * 32;
    const int rblk = rowBase >> 4;
    const int l15 = lane & 15, lg = lane >> 4;

    f32x4 acc[2][8];
#pragma unroll
    for (int rt = 0; rt < 2; ++rt)
#pragma unroll
        for (int ct = 0; ct < 8; ++ct) acc[rt][ct] = (f32x4){0.f, 0.f, 0.f, 0.f};

#pragma unroll
    for (int ks = 0; ks < 4; ++ks) {
        bf16x8 ahi[2], alo[2];
#pragma unroll
        for (int rt = 0; rt < 2; ++rt) {
            int r = rowBase + rt * 16 + l15;
            if (F32A) {
                float av[8];
                if (r < N) {
                    const float* ap = A + (size_t)r * 128 + ks * 32 + lg * 8;
                    float4 a0 = *(const float4*)(ap);
                    float4 a1 = *(const float4*)(ap + 4);
                    av[0] = a0.x; av[1] = a0.y; av[2] = a0.z; av[3] = a0.w;
                    av[4] = a1.x; av[5] = a1.y; av[6] = a1.z; av[7] = a1.w;
                } else {
#pragma unroll
                    for (int j = 0; j < 8; ++j) av[j] = 0.f;
                }
#pragma unroll
                for (int j = 0; j < 8; ++j) {
                    ushort_t h = f2bf(av[j]);
                    ahi[rt][j] = (short)h;
                    alo[rt][j] = (short)f2bf(av[j] - bf2f(h));
                }
            } else {
                if (r < N) {
                    ahi[rt] = *(const bf16x8*)(a_bf + (size_t)(rblk + rt) * 2048 + (ks * 4 + lg) * 128 + l15 * 8);
                } else {
                    bf16x8 z = {0, 0, 0, 0, 0, 0, 0, 0};
                    ahi[rt] = z;
                }
            }
        }
#pragma unroll
        for (int ct = 0; ct < 8; ++ct) {
            size_t boff = (size_t)(((ct * 4 + ks) * 64 + lane) * 8);
            bf16x8 bhi = *(const bf16x8*)(wt_hi + boff);
            bf16x8 blo = *(const bf16x8*)(wt_lo + boff);
            acc[0][ct] = __builtin_amdgcn_mfma_f32_16x16x32_bf16(ahi[0], bhi, acc[0][ct], 0, 0, 0);
            acc[1][ct] = __builtin_amdgcn_mfma_f32_16x16x32_bf16(ahi[1], bhi, acc[1][ct], 0, 0, 0);
            acc[0][ct] = __builtin_amdgcn_mfma_f32_16x16x32_bf16(ahi[0], blo, acc[0][ct], 0, 0, 0);
            acc[1][ct] = __builtin_amdgcn_mfma_f32_16x16x32_bf16(ahi[1], blo, acc[1][ct], 0, 0, 0);
            if (F32A) {
                acc[0][ct] = __builtin_amdgcn_mfma_f32_16x16x32_bf16(alo[0], bhi, acc[0][ct], 0, 0, 0);
                acc[1][ct] = __builtin_amdgcn_mfma_f32_16x16x32_bf16(alo[1], bhi, acc[1][ct], 0, 0, 0);
            }
        }
    }

#pragma unroll
    for (int rt = 0; rt < 2; ++rt) {
#pragma unroll
        for (int reg = 0; reg < 4; ++reg) {
            int row = rowBase + rt * 16 + lg * 4 + reg;
            if (row >= N) continue;
            if (MODE == 0) {
                int r16 = lg * 4 + reg;
#pragma unroll
                for (int ct = 0; ct < 8; ++ct) {
                    int colc = ct * 16 + l15;
                    float v = acc[rt][ct][reg] + bias[colc];
                    v = v > 0.f ? v : expf(v) - 1.f;
                    out0[(size_t)(rblk + rt) * 2048 + (colc >> 3) * 128 + r16 * 8 + (colc & 7)] = f2bf(v);
                }
            } else {
                float dv = dinv[row];
#pragma unroll
                for (int ct = 0; ct < 8; ++ct) {
                    int colc = ct * 16 + l15;
                    out0[(size_t)row * 128 + colc] = f2bf(acc[rt][ct][reg] * dv);
                }
            }
        }
    }
}

// ---------------- K3: scatter + gemm1 ----------------
__global__ __launch_bounds__(256) void part_gemm1(const int* __restrict__ erow, const int* __restrict__ ecol,
                                                  const int* __restrict__ brp, const int* __restrict__ basew,
                                                  unsigned int* __restrict__ pairs,
                                                  const float* __restrict__ x,
                                                  const ushort_t* __restrict__ wt_hi,
                                                  const ushort_t* __restrict__ wt_lo,
                                                  const float* __restrict__ lin1_b,
                                                  ushort_t* __restrict__ h) {
    if (blockIdx.x < NPARTB) {
        __shared__ int sbase[NB];
        __shared__ int lcnt[NB];
        const int blk = blockIdx.x, t = threadIdx.x;
        for (int i = t; i < NB; i += 256) {
            sbase[i] = brp[i] + basew[blk * NB + i];
            lcnt[i] = 0;
        }
        __syncthreads();
        const int e0 = blk * PCHUNK;
        const int e1 = min(e0 + PCHUNK, NE);
        for (int e = e0 + t; e < e1; e += 256) {
            int d = ecol[e];
            int b = d / RB;
            int off = atomicAdd(&lcnt[b], 1);
            pairs[sbase[b] + off] = ((unsigned)erow[e] << 8) | (unsigned)(d - b * RB);
        }
    } else {
        gemm_body<true, 0>(blockIdx.x - NPARTB, threadIdx.x, x, nullptr, wt_hi, wt_lo,
                           lin1_b, nullptr, h, NN);
    }
}

// ---------------- fused: bucket_fill + readout0 ----------------
__global__ __launch_bounds__(256) void fill_readout0(const unsigned int* __restrict__ pairs, const int* __restrict__ brp,
                                                     int* __restrict__ rp, float* __restrict__ dinv,
                                                     int* __restrict__ csrc,
                                                     const ushort_t* __restrict__ h,
                                                     const int* __restrict__ batch,
                                                     const float* __restrict__ invcnt,
                                                     float* __restrict__ reps) {
    if (blockIdx.x < NB) {
        __shared__ int cnt[RB];
        __shared__ int cur[RB];
        __shared__ int sc[256];
        const int b = blockIdx.x, t = threadIdx.x;
        const int nbase = b * RB;
        const int s = brp[b], e = brp[b + 1];
        for (int i = t; i < RB; i += 256) cnt[i] = 0;
        __syncthreads();
        for (int i = s + t; i < e; i += 256) atomicAdd(&cnt[pairs[i] & 255u], 1);
        __syncthreads();
        int v = (t < RB) ? cnt[t] : 0;
        sc[t] = v;
        __syncthreads();
        for (int off = 1; off < 256; off <<= 1) {
            int x = (t >= off) ? sc[t - off] : 0;
            __syncthreads();
            sc[t] += x;
            __syncthreads();
        }
        if (t < RB) {
            int ex = s + sc[t] - v;
            int node = nbase + t;
            if (node < NN) {
                rp[node] = ex;
                dinv[node] = rsqrtf((float)v + 1.0f);
            }
            cur[t] = ex;
        }
        __syncthreads();
        for (int i = s + t; i < e; i += 256) {
            unsigned int p = pairs[i];
            int slot = atomicAdd(&cur[p & 255u], 1);
            csrc[slot] = (int)(p >> 8);
        }
    } else {
        int bb = blockIdx.x - NB;
        int g = bb >> 2;
        int part = bb & 3;
        int lo = 0, hi = NN;
        while (lo < hi) { int m = (lo + hi) >> 1; if (batch[m] < g) lo = m + 1; else hi = m; }
        int s = lo;
        lo = 0; hi = NN;
        while (lo < hi) { int m = (lo + hi) >> 1; if (batch[m] < g + 1) lo = m + 1; else hi = m; }
        int e = lo;

        __shared__ float sh[16][136];
        int ns = (int)(threadIdx.x >> 4);
        int L  = (int)(threadIdx.x & 15);
        int c8 = L << 3;
        float acc[8] = {};
        for (int v = s + part + ns * 4; v < e; v += 64) {
            ushort8_t t = *(const ushort8_t*)(h + (size_t)(v >> 4) * 2048 + L * 128 + (v & 15) * 8);
#pragma unroll
            for (int j = 0; j < 8; ++j) acc[j] += bf2f(t[j]);
        }
#pragma unroll
        for (int j = 0; j < 8; ++j) sh[ns][c8 + j] = acc[j];
        __syncthreads();
        if (threadIdx.x < 128) {
            int c = (int)threadIdx.x;
            float sum = 0.f;
#pragma unroll
            for (int k = 0; k < 16; ++k) sum += sh[k][c];
            unsafeAtomicAdd(&reps[(size_t)g * 128 + c], sum * invcnt[g]);
        }
    }
}

// ---------------- standalone GCN gemm (MODE 1) ----------------
__global__ __launch_bounds__(256) void gemm_gcn(const ushort_t* __restrict__ a_bf,
                                                const ushort_t* __restrict__ wt_hi,
                                                const ushort_t* __restrict__ wt_lo,
                                                const float* __restrict__ dinv,
                                                ushort_t* __restrict__ hwb) {
    gemm_body<false, 1>(blockIdx.x, threadIdx.x, nullptr, a_bf, wt_hi, wt_lo,
                        nullptr, dinv, hwb, NN);
}

// ---------------- gather + fused readout, XCD column-sliced ----------------
// blockIdx = chunk*8 + cs; cs = column slice (16 cols), bound to XCD via round-robin.
// 256 thr = 128 nodes x 2 lanes (8 cols each). Per-column summation order identical
// to previous rounds -> bit-identical results.
__global__ __launch_bounds__(256) void gather_agg(const int* __restrict__ rp,
                                                  const int* __restrict__ csrc,
                                                  const float* __restrict__ dinv,
                                                  const ushort_t* __restrict__ hwb,
                                                  const float* __restrict__ bias,
                                                  const int* __restrict__ batch,
                                                  const float* __restrict__ invcnt,
                                                  float* __restrict__ reps,
                                                  ushort_t* __restrict__ h_out) {
    const int cs = (int)(blockIdx.x & 7);
    const int chunk = (int)(blockIdx.x >> 3);
    const int v0 = chunk * GCHUNK;
    const int t = (int)threadIdx.x;
    const int ns = t >> 1;
    const int half = t & 1;
    const int c8 = cs * 16 + half * 8;
    int v = v0 + ns;

    __shared__ float sh[128][16];
    __shared__ int gid[128];
    if (t < 128) {
        int bidx = v0 + t;
        if (bidx > NN - 1) bidx = NN - 1;
        gid[t] = batch[bidx];
    }

    float acc[8] = {};
    if (v < NN) {
        int s = rp[v], e = rp[v + 1];
        int i = s;
        for (; i + 8 <= e; i += 8) {
            int u[8];
#pragma unroll
            for (int k = 0; k < 8; ++k) u[k] = csrc[i + k];
            ushort8_t r[8];
#pragma unroll
            for (int k = 0; k < 8; ++k) r[k] = *(const ushort8_t*)(hwb + (size_t)u[k] * 128 + c8);
#pragma unroll
            for (int k = 0; k < 8; ++k)
#pragma unroll
                for (int j = 0; j < 8; ++j) acc[j] += bf2f(r[k][j]);
        }
        for (; i < e; ++i) {
            int u = csrc[i];
            ushort8_t r0 = *(const ushort8_t*)(hwb + (size_t)u * 128 + c8);
#pragma unroll
            for (int j = 0; j < 8; ++j) acc[j] += bf2f(r0[j]);
        }

        float di = dinv[v];
        ushort8_t sv = *(const ushort8_t*)(hwb + (size_t)v * 128 + c8);
        ushort8_t o;
#pragma unroll
        for (int j = 0; j < 8; ++j) {
            float tv = di * (acc[j] + bf2f(sv[j])) + bias[c8 + j];
            tv = tv > 0.f ? tv : expf(tv) - 1.f;
            acc[j] = tv;
            o[j] = f2bf(tv);
        }
        // PERM write (c8 is 8-aligned)
        *(ushort8_t*)(h_out + (size_t)(v >> 4) * 2048 + (c8 >> 3) * 128 + (v & 15) * 8) = o;
    } else {
#pragma unroll
        for (int j = 0; j < 8; ++j) acc[j] = 0.f;
    }

    // fused readout for this 16-col slice
#pragma unroll
    for (int j = 0; j < 8; ++j) sh[ns][half * 8 + j] = acc[j];
    __syncthreads();
    if (t < 128) {
        int sc = t >> 4;          // 16-node subchunk 0..7
        int c  = t & 15;          // column within slice
        int base = sc * 16;
        float run = sh[base][c];
        int cg = gid[base];
#pragma unroll
        for (int k = 1; k < 16; ++k) {
            int g2 = gid[base + k];
            if (g2 != cg) {
                unsafeAtomicAdd(&reps[(size_t)cg * 128 + cs * 16 + c], run * invcnt[cg]);
                run = 0.f;
                cg = g2;
            }
            run += sh[base + k][c];
        }
        unsafeAtomicAdd(&reps[(size_t)cg * 128 + cs * 16 + c], run * invcnt[cg]);
    }
}

// ---------------- fused head ----------------
__global__ __launch_bounds__(128) void head_fused(const float* __restrict__ reps,
                                                  const float* __restrict__ wout,
                                                  const float* __restrict__ bout,
                                                  const float* __restrict__ cw,
                                                  const float* __restrict__ cb,
                                                  float* __restrict__ out) {
    __shared__ float rrow[128];
    __shared__ float gg[128];
    __shared__ float lg[10];
    int t = threadIdx.x;
    int g = blockIdx.x;
    rrow[t] = reps[(size_t)g * 128 + t];
    __syncthreads();
    float a = bout[t];
    for (int k = 0; k < 128; ++k) a = fmaf(rrow[k], wout[k * 128 + t], a);
    a = a > 0.f ? a : expf(a) - 1.f;
    gg[t] = a;
    __syncthreads();
    if (t < 10) {
        float s = cb[t];
        for (int k = 0; k < 128; ++k) s = fmaf(gg[k], cw[k * 10 + t], s);
        lg[t] = s;
    }
    __syncthreads();
    if (t == 0) {
        float m = lg[0];
#pragma unroll
        for (int j = 1; j < 10; ++j) m = fmaxf(m, lg[j]);
        float se = 0.f;
#pragma unroll
        for (int j = 0; j < 10; ++j) se += expf(lg[j] - m);
        float L = logf(se);
#pragma unroll
        for (int j = 0; j < 10; ++j) out[(size_t)g * 10 + j] = lg[j] - m - L;
    }
}

extern "C" void kernel_launch(void* const* d_in, const int* in_sizes, int n_in,
                              void* d_out, int out_size, void* d_ws, size_t ws_size,
                              hipStream_t stream) {
    const float* x        = (const float*)d_in[0];
    const float* lin1_w   = (const float*)d_in[1];
    const float* lin1_b   = (const float*)d_in[2];
    const float* gcn_w    = (const float*)d_in[3];
    const float* gcn_b    = (const float*)d_in[4];
    const float* lin_out_w= (const float*)d_in[5];
    const float* lin_out_b= (const float*)d_in[6];
    const float* cls_w    = (const float*)d_in[7];
    const float* cls_b    = (const float*)d_in[8];
    const int*   ei       = (const int*)d_in[9];
    const int*   batch    = (const int*)d_in[10];
    float* out = (float*)d_out;

    const int* erow = ei;
    const int* ecol = ei + NE;

    ushort_t* h     = (ushort_t*)d_ws;                     // NN*128 bf16 (PERM)
    ushort_t* hwb   = h + (size_t)NN * 128;                // NN*128 bf16 (row-major)
    float*    dinv  = (float*)(hwb + (size_t)NN * 128);    // NN
    float*    reps  = dinv + NN;                           // NG*128
    float*    invcnt= reps + (size_t)NG * 128;             // NG
    int*      rp    = (int*)(invcnt + NG);                 // NN+1
    int*      csrc  = rp + NN + 1;                         // NE
    int*      brp   = csrc + NE;                           // NB+1
    int*      bcount= brp + NB + 1;                        // NPARTB*NB
    int*      basew = bcount + NPARTB * NB;                // NPARTB*NB
    ushort_t* wt_hi = (ushort_t*)(basew + NPARTB * NB);    // 4*16384
    ushort_t* wt_lo = wt_hi + 4 * 16384;                   // 4*16384
    unsigned int* pairs = (unsigned int*)(wt_lo + 4 * 16384);  // NE

    hipMemsetAsync(reps, 0, (size_t)NG * 128 * sizeof(float), stream);

    hist_prepw<<<NPARTB + 32, 256, 0, stream>>>(ecol, bcount, lin1_w, gcn_w, wt_hi, wt_lo);
    scan_bases<<<1, NB, 0, stream>>>(bcount, basew, brp, rp, batch, invcnt);
    part_gemm1<<<NPARTB + GEMM_GRID, 256, 0, stream>>>(erow, ecol, brp, basew, pairs,
                                                       x, wt_hi, wt_lo, lin1_b, h);
    fill_readout0<<<NB + NG * 4, 256, 0, stream>>>(pairs, brp, rp, dinv, csrc,
                                                   h, batch, invcnt, reps);

    for (int i = 0; i < 3; ++i) {
        gemm_gcn<<<GEMM_GRID, 256, 0, stream>>>(h, wt_hi + (size_t)(i + 1) * 16384,
                                                wt_lo + (size_t)(i + 1) * 16384,
                                                dinv, hwb);
        gather_agg<<<NCHUNKS * 8, 256, 0, stream>>>(rp, csrc, dinv, hwb,
                                                    gcn_b + (size_t)i * 128,
                                                    batch, invcnt, reps, h);
    }

    head_fused<<<NG, 128, 0, stream>>>(reps, lin_out_w, lin_out_b, cls_w, cls_b, out);
}

// Round 15
// 438.140 us; speedup vs baseline: 1.8855x; 1.8855x over previous
//
#include <hip/hip_runtime.h>
#include <hip/hip_bf16.h>
#include <math.h>

#define NN 100000
#define NE 1600000
#define HID 128
#define NG 512
#define NB 512          // dst buckets
#define RB 196          // nodes per bucket (512*196 = 100352 >= NN)
#define PCHUNK 16384
#define NPARTB ((NE + PCHUNK - 1) / PCHUNK)   // 98
#define GEMM_GRID ((NN + 127) / 128)          // 782
#define NCONV (NN / 16)                       // 6250 (NN is a multiple of 16)

typedef unsigned short ushort_t;
typedef __attribute__((ext_vector_type(8))) short bf16x8;
typedef __attribute__((ext_vector_type(8))) unsigned short ushort8_t;
typedef __attribute__((ext_vector_type(4))) float f32x4;

__device__ __forceinline__ ushort_t f2bf(float v) {
    unsigned u = __float_as_uint(v);
    unsigned r = (u + 0x7FFF + ((u >> 16) & 1)) >> 16;
    return (ushort_t)r;
}
__device__ __forceinline__ float bf2f(ushort_t u) {
    return __uint_as_float((unsigned)u << 16);
}

// PERM layout for h/x: node v, col k -> (v>>4)*2048 + (k>>3)*128 + (v&15)*8 + (k&7)

// ---------------- K1: histogram (0..97) + weight prep (98..129) + x convert (130..) ----------------
__global__ __launch_bounds__(256) void hist_prepw(const int* __restrict__ ecol, int* __restrict__ bcount,
                                                  const float* __restrict__ lin1_w,
                                                  const float* __restrict__ gcn_w,
                                                  ushort_t* __restrict__ wt_hi,
                                                  ushort_t* __restrict__ wt_lo,
                                                  const float* __restrict__ x,
                                                  ushort_t* __restrict__ xp_hi,
                                                  ushort_t* __restrict__ xp_lo) {
    if (blockIdx.x < NPARTB) {
        __shared__ int lh[NB];
        const int blk = blockIdx.x, t = threadIdx.x;
        for (int i = t; i < NB; i += 256) lh[i] = 0;
        __syncthreads();
        const int e0 = blk * PCHUNK;
        const int e1 = min(e0 + PCHUNK, NE);
        for (int e = e0 + t; e < e1; e += 256) atomicAdd(&lh[ecol[e] / RB], 1);
        __syncthreads();
        for (int i = t; i < NB; i += 256) bcount[blk * NB + i] = lh[i];
    } else if (blockIdx.x < NPARTB + 32) {
        int mb = blockIdx.x - NPARTB;
        int m = mb >> 3;
        int chunk = mb & 7;
        const float* W = (m == 0) ? lin1_w : gcn_w + (size_t)(m - 1) * 16384;
        ushort_t* hi = wt_hi + (size_t)m * 16384;
        ushort_t* lo = wt_lo + (size_t)m * 16384;
        for (int i = chunk * 2048 + threadIdx.x; i < (chunk + 1) * 2048; i += 256) {
            int j = i & 7;
            int lane = (i >> 3) & 63;
            int ks = (i >> 9) & 3;
            int ct = (i >> 11) & 7;
            int n = ct * 16 + (lane & 15);
            int k = ks * 32 + (lane >> 4) * 8 + j;
            float v = W[k * 128 + n];
            ushort_t h = f2bf(v);
            hi[i] = h;
            lo[i] = f2bf(v - bf2f(h));
        }
    } else {
        // convert x (fp32 row-major) -> PERM bf16 hi/lo; block = 16 nodes (exact, NN%16==0)
        int cb = (int)blockIdx.x - NPARTB - 32;     // 0..NCONV-1
        int t = (int)threadIdx.x;
        int ns = t >> 4, L = t & 15;
        int v = cb * 16 + ns;
        const float* ap = x + (size_t)v * 128 + L * 8;
        float4 a0 = *(const float4*)(ap);
        float4 a1 = *(const float4*)(ap + 4);
        float av[8] = {a0.x, a0.y, a0.z, a0.w, a1.x, a1.y, a1.z, a1.w};
        ushort8_t hi8, lo8;
#pragma unroll
        for (int j = 0; j < 8; ++j) {
            ushort_t h = f2bf(av[j]);
            hi8[j] = h;
            lo8[j] = f2bf(av[j] - bf2f(h));
        }
        size_t off = (size_t)cb * 2048 + L * 128 + ns * 8;
        *(ushort8_t*)(xp_hi + off) = hi8;
        *(ushort8_t*)(xp_lo + off) = lo8;
    }
}

// ---------------- K2: per-bucket block bases + bucket scan + invcnt ----------------
__global__ __launch_bounds__(NB) void scan_bases(const int* __restrict__ bcount, int* __restrict__ basew,
                                                 int* __restrict__ brp, int* __restrict__ rp,
                                                 const int* __restrict__ batch, float* __restrict__ invcnt) {
    __shared__ int s[NB];
    int t = threadIdx.x;
    int tot = 0;
    for (int k = 0; k < NPARTB; ++k) {
        int c = bcount[k * NB + t];
        basew[k * NB + t] = tot;
        tot += c;
    }
    s[t] = tot;
    __syncthreads();
    for (int off = 1; off < NB; off <<= 1) {
        int x = (t >= off) ? s[t - off] : 0;
        __syncthreads();
        s[t] += x;
        __syncthreads();
    }
    int ex = s[t] - tot;
    brp[t] = ex;
    if (t == NB - 1) { brp[NB] = s[t]; rp[NN] = s[t]; }

    int lo = 0, hi = NN;
    while (lo < hi) { int m = (lo + hi) >> 1; if (batch[m] < t) lo = m + 1; else hi = m; }
    int s0 = lo;
    lo = 0; hi = NN;
    while (lo < hi) { int m = (lo + hi) >> 1; if (batch[m] < t + 1) lo = m + 1; else hi = m; }
    int c = lo - s0;
    invcnt[t] = 1.0f / (float)(c > 0 ? c : 1);
}

// ---------------- GEMM body ----------------
// AMODE 0: A = single bf16 PERM (2-term, W hi/lo). AMODE 1: A = hi/lo bf16 PERM (3-term).
// MODE 0: out0 = PERM bf16(elu(acc+bias)). MODE 1: out0 = row-major bf16(dinv*acc).
template<int AMODE, int MODE>
__device__ __forceinline__ void gemm_body(int bid, int tid,
                                          const ushort_t* __restrict__ a_hi,
                                          const ushort_t* __restrict__ a_lo,
                                          const ushort_t* __restrict__ wt_hi,
                                          const ushort_t* __restrict__ wt_lo,
                                          const float* __restrict__ bias,
                                          const float* __restrict__ dinv,
                                          ushort_t* __restrict__ out0,
                                          int N) {
    const int lane = tid & 63;
    const int wid = tid >> 6;
    const int rowBase = bid * 128 + wid * 32;
    const int rblk = rowBase >> 4;
    const int l15 = lane & 15, lg = lane >> 4;

    f32x4 acc[2][8];
#pragma unroll
    for (int rt = 0; rt < 2; ++rt)
#pragma unroll
        for (int ct = 0; ct < 8; ++ct) acc[rt][ct] = (f32x4){0.f, 0.f, 0.f, 0.f};

#pragma unroll
    for (int ks = 0; ks < 4; ++ks) {
        bf16x8 ahi[2], alo[2];
#pragma unroll
        for (int rt = 0; rt < 2; ++rt) {
            int r = rowBase + rt * 16 + l15;
            if (r < N) {
                size_t aoff = (size_t)(rblk + rt) * 2048 + (ks * 4 + lg) * 128 + l15 * 8;
                ahi[rt] = *(const bf16x8*)(a_hi + aoff);
                if (AMODE == 1) alo[rt] = *(const bf16x8*)(a_lo + aoff);
            } else {
                bf16x8 z = {0, 0, 0, 0, 0, 0, 0, 0};
                ahi[rt] = z;
                if (AMODE == 1) alo[rt] = z;
            }
        }
#pragma unroll
        for (int ct = 0; ct < 8; ++ct) {
            size_t boff = (size_t)(((ct * 4 + ks) * 64 + lane) * 8);
            bf16x8 bhi = *(const bf16x8*)(wt_hi + boff);
            bf16x8 blo = *(const bf16x8*)(wt_lo + boff);
            acc[0][ct] = __builtin_amdgcn_mfma_f32_16x16x32_bf16(ahi[0], bhi, acc[0][ct], 0, 0, 0);
            acc[1][ct] = __builtin_amdgcn_mfma_f32_16x16x32_bf16(ahi[1], bhi, acc[1][ct], 0, 0, 0);
            acc[0][ct] = __builtin_amdgcn_mfma_f32_16x16x32_bf16(ahi[0], blo, acc[0][ct], 0, 0, 0);
            acc[1][ct] = __builtin_amdgcn_mfma_f32_16x16x32_bf16(ahi[1], blo, acc[1][ct], 0, 0, 0);
            if (AMODE == 1) {
                acc[0][ct] = __builtin_amdgcn_mfma_f32_16x16x32_bf16(alo[0], bhi, acc[0][ct], 0, 0, 0);
                acc[1][ct] = __builtin_amdgcn_mfma_f32_16x16x32_bf16(alo[1], bhi, acc[1][ct], 0, 0, 0);
            }
        }
    }

#pragma unroll
    for (int rt = 0; rt < 2; ++rt) {
#pragma unroll
        for (int reg = 0; reg < 4; ++reg) {
            int row = rowBase + rt * 16 + lg * 4 + reg;
            if (row >= N) continue;
            if (MODE == 0) {
                int r16 = lg * 4 + reg;
#pragma unroll
                for (int ct = 0; ct < 8; ++ct) {
                    int colc = ct * 16 + l15;
                    float v = acc[rt][ct][reg] + bias[colc];
                    v = v > 0.f ? v : expf(v) - 1.f;
                    out0[(size_t)(rblk + rt) * 2048 + (colc >> 3) * 128 + r16 * 8 + (colc & 7)] = f2bf(v);
                }
            } else {
                float dv = dinv[row];
#pragma unroll
                for (int ct = 0; ct < 8; ++ct) {
                    int colc = ct * 16 + l15;
                    out0[(size_t)row * 128 + colc] = f2bf(acc[rt][ct][reg] * dv);
                }
            }
        }
    }
}

// ---------------- K3: scatter (atomic-free bases) + gemm1 (PERM 3-term) ----------------
__global__ __launch_bounds__(256) void part_gemm1(const int* __restrict__ erow, const int* __restrict__ ecol,
                                                  const int* __restrict__ brp, const int* __restrict__ basew,
                                                  unsigned int* __restrict__ pairs,
                                                  const ushort_t* __restrict__ xp_hi,
                                                  const ushort_t* __restrict__ xp_lo,
                                                  const ushort_t* __restrict__ wt_hi,
                                                  const ushort_t* __restrict__ wt_lo,
                                                  const float* __restrict__ lin1_b,
                                                  ushort_t* __restrict__ h) {
    if (blockIdx.x < NPARTB) {
        __shared__ int sbase[NB];
        __shared__ int lcnt[NB];
        const int blk = blockIdx.x, t = threadIdx.x;
        for (int i = t; i < NB; i += 256) {
            sbase[i] = brp[i] + basew[blk * NB + i];
            lcnt[i] = 0;
        }
        __syncthreads();
        const int e0 = blk * PCHUNK;
        const int e1 = min(e0 + PCHUNK, NE);
        for (int e = e0 + t; e < e1; e += 256) {
            int d = ecol[e];
            int b = d / RB;
            int off = atomicAdd(&lcnt[b], 1);
            pairs[sbase[b] + off] = ((unsigned)erow[e] << 8) | (unsigned)(d - b * RB);
        }
    } else {
        gemm_body<1, 0>(blockIdx.x - NPARTB, threadIdx.x, xp_hi, xp_lo, wt_hi, wt_lo,
                        lin1_b, nullptr, h, NN);
    }
}

// ---------------- fused: bucket_fill + readout0 ----------------
__global__ __launch_bounds__(256) void fill_readout0(const unsigned int* __restrict__ pairs, const int* __restrict__ brp,
                                                     int* __restrict__ rp, float* __restrict__ dinv,
                                                     int* __restrict__ csrc,
                                                     const ushort_t* __restrict__ h,
                                                     const int* __restrict__ batch,
                                                     const float* __restrict__ invcnt,
                                                     float* __restrict__ reps) {
    if (blockIdx.x < NB) {
        __shared__ int cnt[RB];
        __shared__ int cur[RB];
        __shared__ int sc[256];
        const int b = blockIdx.x, t = threadIdx.x;
        const int nbase = b * RB;
        const int s = brp[b], e = brp[b + 1];
        for (int i = t; i < RB; i += 256) cnt[i] = 0;
        __syncthreads();
        for (int i = s + t; i < e; i += 256) atomicAdd(&cnt[pairs[i] & 255u], 1);
        __syncthreads();
        int v = (t < RB) ? cnt[t] : 0;
        sc[t] = v;
        __syncthreads();
        for (int off = 1; off < 256; off <<= 1) {
            int x = (t >= off) ? sc[t - off] : 0;
            __syncthreads();
            sc[t] += x;
            __syncthreads();
        }
        if (t < RB) {
            int ex = s + sc[t] - v;
            int node = nbase + t;
            if (node < NN) {
                rp[node] = ex;
                dinv[node] = rsqrtf((float)v + 1.0f);
            }
            cur[t] = ex;
        }
        __syncthreads();
        for (int i = s + t; i < e; i += 256) {
            unsigned int p = pairs[i];
            int slot = atomicAdd(&cur[p & 255u], 1);
            csrc[slot] = (int)(p >> 8);
        }
    } else {
        int bb = blockIdx.x - NB;
        int g = bb >> 2;
        int part = bb & 3;
        int lo = 0, hi = NN;
        while (lo < hi) { int m = (lo + hi) >> 1; if (batch[m] < g) lo = m + 1; else hi = m; }
        int s = lo;
        lo = 0; hi = NN;
        while (lo < hi) { int m = (lo + hi) >> 1; if (batch[m] < g + 1) lo = m + 1; else hi = m; }
        int e = lo;

        __shared__ float sh[16][136];
        int ns = (int)(threadIdx.x >> 4);
        int L  = (int)(threadIdx.x & 15);
        int c8 = L << 3;
        float acc[8] = {};
        for (int v = s + part + ns * 4; v < e; v += 64) {
            ushort8_t t = *(const ushort8_t*)(h + (size_t)(v >> 4) * 2048 + L * 128 + (v & 15) * 8);
#pragma unroll
            for (int j = 0; j < 8; ++j) acc[j] += bf2f(t[j]);
        }
#pragma unroll
        for (int j = 0; j < 8; ++j) sh[ns][c8 + j] = acc[j];
        __syncthreads();
        if (threadIdx.x < 128) {
            int c = (int)threadIdx.x;
            float sum = 0.f;
#pragma unroll
            for (int k = 0; k < 16; ++k) sum += sh[k][c];
            unsafeAtomicAdd(&reps[(size_t)g * 128 + c], sum * invcnt[g]);
        }
    }
}

// ---------------- standalone GCN gemm (MODE 1) ----------------
__global__ __launch_bounds__(256) void gemm_gcn(const ushort_t* __restrict__ a_bf,
                                                const ushort_t* __restrict__ wt_hi,
                                                const ushort_t* __restrict__ wt_lo,
                                                const float* __restrict__ dinv,
                                                ushort_t* __restrict__ hwb) {
    gemm_body<0, 1>(blockIdx.x, threadIdx.x, a_bf, nullptr, wt_hi, wt_lo,
                    nullptr, dinv, hwb, NN);
}

// ---------------- gather + fused readout (round-13 version, reverted) ----------------
__global__ __launch_bounds__(256) void gather_agg(const int* __restrict__ rp,
                                                  const int* __restrict__ csrc,
                                                  const float* __restrict__ dinv,
                                                  const ushort_t* __restrict__ hwb,
                                                  const float* __restrict__ bias,
                                                  const int* __restrict__ batch,
                                                  const float* __restrict__ invcnt,
                                                  float* __restrict__ reps,
                                                  ushort_t* __restrict__ h_out) {
    __shared__ float sh[16][136];
    __shared__ int gid[16];
    const int v0 = blockIdx.x * 16;
    const int ns = (int)(threadIdx.x >> 4);
    int v = v0 + ns;
    int L = (int)(threadIdx.x & 15);
    int c8 = L << 3;
    if (threadIdx.x < 16) {
        int bidx = v0 + (int)threadIdx.x;
        if (bidx > NN - 1) bidx = NN - 1;
        gid[threadIdx.x] = batch[bidx];
    }

    float acc[8] = {};
    if (v < NN) {
        int s = rp[v], e = rp[v + 1];
        int i = s;
        for (; i + 16 <= e; i += 16) {
            int u[16];
#pragma unroll
            for (int k = 0; k < 16; ++k) u[k] = csrc[i + k];
            ushort8_t r[16];
#pragma unroll
            for (int k = 0; k < 16; ++k) r[k] = *(const ushort8_t*)(hwb + (size_t)u[k] * 128 + c8);
#pragma unroll
            for (int k = 0; k < 16; ++k)
#pragma unroll
                for (int j = 0; j < 8; ++j) acc[j] += bf2f(r[k][j]);
        }
        for (; i + 8 <= e; i += 8) {
            int u[8];
#pragma unroll
            for (int k = 0; k < 8; ++k) u[k] = csrc[i + k];
            ushort8_t r[8];
#pragma unroll
            for (int k = 0; k < 8; ++k) r[k] = *(const ushort8_t*)(hwb + (size_t)u[k] * 128 + c8);
#pragma unroll
            for (int k = 0; k < 8; ++k)
#pragma unroll
                for (int j = 0; j < 8; ++j) acc[j] += bf2f(r[k][j]);
        }
        for (; i < e; ++i) {
            int u = csrc[i];
            ushort8_t r0 = *(const ushort8_t*)(hwb + (size_t)u * 128 + c8);
#pragma unroll
            for (int j = 0; j < 8; ++j) acc[j] += bf2f(r0[j]);
        }

        float di = dinv[v];
        ushort8_t sv = *(const ushort8_t*)(hwb + (size_t)v * 128 + c8);
        ushort8_t o;
#pragma unroll
        for (int j = 0; j < 8; ++j) {
            float t = di * (acc[j] + bf2f(sv[j])) + bias[c8 + j];
            t = t > 0.f ? t : expf(t) - 1.f;
            acc[j] = t;
            o[j] = f2bf(t);
        }
        *(ushort8_t*)(h_out + (size_t)blockIdx.x * 2048 + L * 128 + ns * 8) = o;
    } else {
#pragma unroll
        for (int j = 0; j < 8; ++j) acc[j] = 0.f;
    }

#pragma unroll
    for (int j = 0; j < 8; ++j) sh[ns][c8 + j] = acc[j];
    __syncthreads();
    if (threadIdx.x < 128) {
        int c = (int)threadIdx.x;
        int nvalid = NN - v0;
        if (nvalid > 16) nvalid = 16;
        float run = sh[0][c];
        int cg = gid[0];
        for (int k = 1; k < nvalid; ++k) {
            int g2 = gid[k];
            if (g2 != cg) {
                unsafeAtomicAdd(&reps[(size_t)cg * 128 + c], run * invcnt[cg]);
                run = 0.f;
                cg = g2;
            }
            run += sh[k][c];
        }
        unsafeAtomicAdd(&reps[(size_t)cg * 128 + c], run * invcnt[cg]);
    }
}

// ---------------- fused head ----------------
__global__ __launch_bounds__(128) void head_fused(const float* __restrict__ reps,
                                                  const float* __restrict__ wout,
                                                  const float* __restrict__ bout,
                                                  const float* __restrict__ cw,
                                                  const float* __restrict__ cb,
                                                  float* __restrict__ out) {
    __shared__ float rrow[128];
    __shared__ float gg[128];
    __shared__ float lg[10];
    int t = threadIdx.x;
    int g = blockIdx.x;
    rrow[t] = reps[(size_t)g * 128 + t];
    __syncthreads();
    float a = bout[t];
    for (int k = 0; k < 128; ++k) a = fmaf(rrow[k], wout[k * 128 + t], a);
    a = a > 0.f ? a : expf(a) - 1.f;
    gg[t] = a;
    __syncthreads();
    if (t < 10) {
        float s = cb[t];
        for (int k = 0; k < 128; ++k) s = fmaf(gg[k], cw[k * 10 + t], s);
        lg[t] = s;
    }
    __syncthreads();
    if (t == 0) {
        float m = lg[0];
#pragma unroll
        for (int j = 1; j < 10; ++j) m = fmaxf(m, lg[j]);
        float se = 0.f;
#pragma unroll
        for (int j = 0; j < 10; ++j) se += expf(lg[j] - m);
        float L = logf(se);
#pragma unroll
        for (int j = 0; j < 10; ++j) out[(size_t)g * 10 + j] = lg[j] - m - L;
    }
}

extern "C" void kernel_launch(void* const* d_in, const int* in_sizes, int n_in,
                              void* d_out, int out_size, void* d_ws, size_t ws_size,
                              hipStream_t stream) {
    const float* x        = (const float*)d_in[0];
    const float* lin1_w   = (const float*)d_in[1];
    const float* lin1_b   = (const float*)d_in[2];
    const float* gcn_w    = (const float*)d_in[3];
    const float* gcn_b    = (const float*)d_in[4];
    const float* lin_out_w= (const float*)d_in[5];
    const float* lin_out_b= (const float*)d_in[6];
    const float* cls_w    = (const float*)d_in[7];
    const float* cls_b    = (const float*)d_in[8];
    const int*   ei       = (const int*)d_in[9];
    const int*   batch    = (const int*)d_in[10];
    float* out = (float*)d_out;

    const int* erow = ei;
    const int* ecol = ei + NE;

    ushort_t* h     = (ushort_t*)d_ws;                     // NN*128 bf16 (PERM)
    ushort_t* hwb   = h + (size_t)NN * 128;                // NN*128 bf16 (row-major); aliased as xp_hi pre-layer0
    float*    dinv  = (float*)(hwb + (size_t)NN * 128);    // NN
    float*    reps  = dinv + NN;                           // NG*128
    float*    invcnt= reps + (size_t)NG * 128;             // NG
    int*      rp    = (int*)(invcnt + NG);                 // NN+1
    int*      csrc  = rp + NN + 1;                         // NE
    int*      brp   = csrc + NE;                           // NB+1
    int*      bcount= brp + NB + 1;                        // NPARTB*NB
    int*      basew = bcount + NPARTB * NB;                // NPARTB*NB
    ushort_t* wt_hi = (ushort_t*)(basew + NPARTB * NB);    // 4*16384
    ushort_t* wt_lo = wt_hi + 4 * 16384;                   // 4*16384
    unsigned int* pairs = (unsigned int*)(wt_lo + 4 * 16384);  // NE
    ushort_t* xp_lo = (ushort_t*)(pairs + NE);             // NN*128 bf16 (PERM)
    ushort_t* xp_hi = hwb;                                 // alias: dead before gemm_gcn writes hwb

    hipMemsetAsync(reps, 0, (size_t)NG * 128 * sizeof(float), stream);

    // CSR hist + weight prep + x->PERM convert (all independent)
    hist_prepw<<<NPARTB + 32 + NCONV, 256, 0, stream>>>(ecol, bcount, lin1_w, gcn_w,
                                                        wt_hi, wt_lo, x, xp_hi, xp_lo);
    scan_bases<<<1, NB, 0, stream>>>(bcount, basew, brp, rp, batch, invcnt);
    part_gemm1<<<NPARTB + GEMM_GRID, 256, 0, stream>>>(erow, ecol, brp, basew, pairs,
                                                       xp_hi, xp_lo, wt_hi, wt_lo, lin1_b, h);
    fill_readout0<<<NB + NG * 4, 256, 0, stream>>>(pairs, brp, rp, dinv, csrc,
                                                   h, batch, invcnt, reps);

    for (int i = 0; i < 3; ++i) {
        gemm_gcn<<<GEMM_GRID, 256, 0, stream>>>(h, wt_hi + (size_t)(i + 1) * 16384,
                                                wt_lo + (size_t)(i + 1) * 16384,
                                                dinv, hwb);
        gather_agg<<<(NN + 15) / 16, 256, 0, stream>>>(rp, csrc, dinv, hwb,
                                                       gcn_b + (size_t)i * 128,
                                                       batch, invcnt, reps, h);
    }

    head_fused<<<NG, 128, 0, stream>>>(reps, lin_out_w, lin_out_b, cls_w, cls_b, out);
}

// Round 16
// 428.093 us; speedup vs baseline: 1.9297x; 1.0235x over previous
//
#include <hip/hip_runtime.h>
#include <hip/hip_bf16.h>
#include <math.h>

#define NN 100000
#define NE 1600000
#define HID 128
#define NG 512
#define NB 512          // dst buckets
#define RB 196          // nodes per bucket (512*196 = 100352 >= NN)
#define PCHUNK 16384
#define NPARTB ((NE + PCHUNK - 1) / PCHUNK)   // 98
#define GEMM_GRID ((NN + 127) / 128)          // 782

typedef unsigned short ushort_t;
typedef __attribute__((ext_vector_type(8))) short bf16x8;
typedef __attribute__((ext_vector_type(8))) unsigned short ushort8_t;
typedef __attribute__((ext_vector_type(4))) float f32x4;

__device__ __forceinline__ ushort_t f2bf(float v) {
    unsigned u = __float_as_uint(v);
    unsigned r = (u + 0x7FFF + ((u >> 16) & 1)) >> 16;
    return (ushort_t)r;
}
__device__ __forceinline__ float bf2f(ushort_t u) {
    return __uint_as_float((unsigned)u << 16);
}

// PERM layout for h: node v, col k -> (v>>4)*2048 + (k>>3)*128 + (v&15)*8 + (k&7)

// ---------------- K1: per-block bucket histogram + weight prep ----------------
__global__ __launch_bounds__(256) void hist_prepw(const int* __restrict__ ecol, int* __restrict__ bcount,
                                                  const float* __restrict__ lin1_w,
                                                  const float* __restrict__ gcn_w,
                                                  ushort_t* __restrict__ wt_hi,
                                                  ushort_t* __restrict__ wt_lo) {
    if (blockIdx.x < NPARTB) {
        __shared__ int lh[NB];
        const int blk = blockIdx.x, t = threadIdx.x;
        for (int i = t; i < NB; i += 256) lh[i] = 0;
        __syncthreads();
        const int e0 = blk * PCHUNK;
        const int e1 = min(e0 + PCHUNK, NE);
        for (int e = e0 + t; e < e1; e += 256) atomicAdd(&lh[ecol[e] / RB], 1);
        __syncthreads();
        for (int i = t; i < NB; i += 256) bcount[blk * NB + i] = lh[i];
    } else {
        int mb = blockIdx.x - NPARTB;
        int m = mb >> 3;
        int chunk = mb & 7;
        const float* W = (m == 0) ? lin1_w : gcn_w + (size_t)(m - 1) * 16384;
        ushort_t* hi = wt_hi + (size_t)m * 16384;
        ushort_t* lo = wt_lo + (size_t)m * 16384;
        for (int i = chunk * 2048 + threadIdx.x; i < (chunk + 1) * 2048; i += 256) {
            int j = i & 7;
            int lane = (i >> 3) & 63;
            int ks = (i >> 9) & 3;
            int ct = (i >> 11) & 7;
            int n = ct * 16 + (lane & 15);
            int k = ks * 32 + (lane >> 4) * 8 + j;
            float v = W[k * 128 + n];
            ushort_t h = f2bf(v);
            hi[i] = h;
            lo[i] = f2bf(v - bf2f(h));
        }
    }
}

// ---------------- K2: block bases + bucket scan + invcnt + zero reps ----------------
__global__ __launch_bounds__(NB) void scan_bases(const int* __restrict__ bcount, int* __restrict__ basew,
                                                 int* __restrict__ brp, int* __restrict__ rp,
                                                 const int* __restrict__ batch, float* __restrict__ invcnt,
                                                 float* __restrict__ reps) {
    __shared__ int s[NB];
    int t = threadIdx.x;
    int tot = 0;
    for (int k = 0; k < NPARTB; ++k) {
        int c = bcount[k * NB + t];
        basew[k * NB + t] = tot;
        tot += c;
    }
    s[t] = tot;
    __syncthreads();
    for (int off = 1; off < NB; off <<= 1) {
        int x = (t >= off) ? s[t - off] : 0;
        __syncthreads();
        s[t] += x;
        __syncthreads();
    }
    int ex = s[t] - tot;
    brp[t] = ex;
    if (t == NB - 1) { brp[NB] = s[t]; rp[NN] = s[t]; }

    int lo = 0, hi = NN;
    while (lo < hi) { int m = (lo + hi) >> 1; if (batch[m] < t) lo = m + 1; else hi = m; }
    int s0 = lo;
    lo = 0; hi = NN;
    while (lo < hi) { int m = (lo + hi) >> 1; if (batch[m] < t + 1) lo = m + 1; else hi = m; }
    int c = lo - s0;
    invcnt[t] = 1.0f / (float)(c > 0 ? c : 1);

    // zero reps row t (replaces hipMemsetAsync)
    f32x4 z = {0.f, 0.f, 0.f, 0.f};
    f32x4* rr = (f32x4*)(reps + (size_t)t * 128);
#pragma unroll
    for (int j = 0; j < 32; ++j) rr[j] = z;
}

// ---------------- GEMM body ----------------
// AMODE 1: A fp32 row-major, in-kernel 3-term split. AMODE 0: A bf16 PERM, 2-term.
// MODE 0: out0 = PERM bf16(elu(acc+bias)). MODE 1: out0 = row-major bf16(dinv*acc), LDS-repacked stores.
template<int AMODE, int MODE>
__device__ __forceinline__ void gemm_body(int bid, int tid,
                                          const float* __restrict__ Af32,
                                          const ushort_t* __restrict__ a_bf,
                                          const ushort_t* __restrict__ wt_hi,
                                          const ushort_t* __restrict__ wt_lo,
                                          const float* __restrict__ bias,
                                          const float* __restrict__ dinv,
                                          ushort_t* __restrict__ out0,
                                          int N,
                                          ushort_t (* __restrict__ lt)[130]) {
    const int lane = tid & 63;
    const int wid = tid >> 6;
    const int rowBase = bid * 128 + wid * 32;
    const int rblk = rowBase >> 4;
    const int l15 = lane & 15, lg = lane >> 4;

    f32x4 acc[2][8];
#pragma unroll
    for (int rt = 0; rt < 2; ++rt)
#pragma unroll
        for (int ct = 0; ct < 8; ++ct) acc[rt][ct] = (f32x4){0.f, 0.f, 0.f, 0.f};

#pragma unroll
    for (int ks = 0; ks < 4; ++ks) {
        bf16x8 ahi[2], alo[2];
#pragma unroll
        for (int rt = 0; rt < 2; ++rt) {
            int r = rowBase + rt * 16 + l15;
            if (AMODE == 1) {
                float av[8];
                if (r < N) {
                    const float* ap = Af32 + (size_t)r * 128 + ks * 32 + lg * 8;
                    float4 a0 = *(const float4*)(ap);
                    float4 a1 = *(const float4*)(ap + 4);
                    av[0] = a0.x; av[1] = a0.y; av[2] = a0.z; av[3] = a0.w;
                    av[4] = a1.x; av[5] = a1.y; av[6] = a1.z; av[7] = a1.w;
                } else {
#pragma unroll
                    for (int j = 0; j < 8; ++j) av[j] = 0.f;
                }
#pragma unroll
                for (int j = 0; j < 8; ++j) {
                    ushort_t h = f2bf(av[j]);
                    ahi[rt][j] = (short)h;
                    alo[rt][j] = (short)f2bf(av[j] - bf2f(h));
                }
            } else {
                if (r < N) {
                    ahi[rt] = *(const bf16x8*)(a_bf + (size_t)(rblk + rt) * 2048 + (ks * 4 + lg) * 128 + l15 * 8);
                } else {
                    bf16x8 z = {0, 0, 0, 0, 0, 0, 0, 0};
                    ahi[rt] = z;
                }
            }
        }
#pragma unroll
        for (int ct = 0; ct < 8; ++ct) {
            size_t boff = (size_t)(((ct * 4 + ks) * 64 + lane) * 8);
            bf16x8 bhi = *(const bf16x8*)(wt_hi + boff);
            bf16x8 blo = *(const bf16x8*)(wt_lo + boff);
            acc[0][ct] = __builtin_amdgcn_mfma_f32_16x16x32_bf16(ahi[0], bhi, acc[0][ct], 0, 0, 0);
            acc[1][ct] = __builtin_amdgcn_mfma_f32_16x16x32_bf16(ahi[1], bhi, acc[1][ct], 0, 0, 0);
            acc[0][ct] = __builtin_amdgcn_mfma_f32_16x16x32_bf16(ahi[0], blo, acc[0][ct], 0, 0, 0);
            acc[1][ct] = __builtin_amdgcn_mfma_f32_16x16x32_bf16(ahi[1], blo, acc[1][ct], 0, 0, 0);
            if (AMODE == 1) {
                acc[0][ct] = __builtin_amdgcn_mfma_f32_16x16x32_bf16(alo[0], bhi, acc[0][ct], 0, 0, 0);
                acc[1][ct] = __builtin_amdgcn_mfma_f32_16x16x32_bf16(alo[1], bhi, acc[1][ct], 0, 0, 0);
            }
        }
    }

    if (MODE == 0) {
#pragma unroll
        for (int rt = 0; rt < 2; ++rt) {
#pragma unroll
            for (int reg = 0; reg < 4; ++reg) {
                int row = rowBase + rt * 16 + lg * 4 + reg;
                if (row >= N) continue;
                int r16 = lg * 4 + reg;
#pragma unroll
                for (int ct = 0; ct < 8; ++ct) {
                    int colc = ct * 16 + l15;
                    float v = acc[rt][ct][reg] + bias[colc];
                    v = v > 0.f ? v : expf(v) - 1.f;
                    out0[(size_t)(rblk + rt) * 2048 + (colc >> 3) * 128 + r16 * 8 + (colc & 7)] = f2bf(v);
                }
            }
        }
    } else {
        // stage to per-wave LDS tile [32][130], then coalesced ushort8 stores
#pragma unroll
        for (int rt = 0; rt < 2; ++rt) {
#pragma unroll
            for (int reg = 0; reg < 4; ++reg) {
                int row = rowBase + rt * 16 + lg * 4 + reg;
                if (row >= N) continue;
                float dv = dinv[row];
                int lr = rt * 16 + lg * 4 + reg;
#pragma unroll
                for (int ct = 0; ct < 8; ++ct) {
                    lt[lr][ct * 16 + l15] = f2bf(acc[rt][ct][reg] * dv);
                }
            }
        }
        __syncthreads();
#pragma unroll
        for (int it = 0; it < 8; ++it) {
            int idx = it * 64 + lane;
            int row = idx >> 4;
            int ch = idx & 15;
            int grow = rowBase + row;
            if (grow < N) {
                ushort8_t v8;
#pragma unroll
                for (int j = 0; j < 8; ++j) v8[j] = lt[row][ch * 8 + j];
                *(ushort8_t*)(out0 + (size_t)grow * 128 + ch * 8) = v8;
            }
        }
    }
}

// ---------------- K3: scatter (atomic-free bases) + gemm1 (fp32 A, 3-term) ----------------
__global__ __launch_bounds__(256) void part_gemm1(const int* __restrict__ erow, const int* __restrict__ ecol,
                                                  const int* __restrict__ brp, const int* __restrict__ basew,
                                                  unsigned int* __restrict__ pairs,
                                                  const float* __restrict__ x,
                                                  const ushort_t* __restrict__ wt_hi,
                                                  const ushort_t* __restrict__ wt_lo,
                                                  const float* __restrict__ lin1_b,
                                                  ushort_t* __restrict__ h) {
    if (blockIdx.x < NPARTB) {
        __shared__ int sbase[NB];
        __shared__ int lcnt[NB];
        const int blk = blockIdx.x, t = threadIdx.x;
        for (int i = t; i < NB; i += 256) {
            sbase[i] = brp[i] + basew[blk * NB + i];
            lcnt[i] = 0;
        }
        __syncthreads();
        const int e0 = blk * PCHUNK;
        const int e1 = min(e0 + PCHUNK, NE);
        for (int e = e0 + t; e < e1; e += 256) {
            int d = ecol[e];
            int b = d / RB;
            int off = atomicAdd(&lcnt[b], 1);
            pairs[sbase[b] + off] = ((unsigned)erow[e] << 8) | (unsigned)(d - b * RB);
        }
    } else {
        gemm_body<1, 0>(blockIdx.x - NPARTB, threadIdx.x, x, nullptr, wt_hi, wt_lo,
                        lin1_b, nullptr, h, NN, nullptr);
    }
}

// ---------------- fused: bucket_fill + readout0 ----------------
__global__ __launch_bounds__(256) void fill_readout0(const unsigned int* __restrict__ pairs, const int* __restrict__ brp,
                                                     int* __restrict__ rp, float* __restrict__ dinv,
                                                     int* __restrict__ csrc,
                                                     const ushort_t* __restrict__ h,
                                                     const int* __restrict__ batch,
                                                     const float* __restrict__ invcnt,
                                                     float* __restrict__ reps) {
    if (blockIdx.x < NB) {
        __shared__ int cnt[RB];
        __shared__ int cur[RB];
        __shared__ int sc[256];
        const int b = blockIdx.x, t = threadIdx.x;
        const int nbase = b * RB;
        const int s = brp[b], e = brp[b + 1];
        for (int i = t; i < RB; i += 256) cnt[i] = 0;
        __syncthreads();
        for (int i = s + t; i < e; i += 256) atomicAdd(&cnt[pairs[i] & 255u], 1);
        __syncthreads();
        int v = (t < RB) ? cnt[t] : 0;
        sc[t] = v;
        __syncthreads();
        for (int off = 1; off < 256; off <<= 1) {
            int x = (t >= off) ? sc[t - off] : 0;
            __syncthreads();
            sc[t] += x;
            __syncthreads();
        }
        if (t < RB) {
            int ex = s + sc[t] - v;
            int node = nbase + t;
            if (node < NN) {
                rp[node] = ex;
                dinv[node] = rsqrtf((float)v + 1.0f);
            }
            cur[t] = ex;
        }
        __syncthreads();
        for (int i = s + t; i < e; i += 256) {
            unsigned int p = pairs[i];
            int slot = atomicAdd(&cur[p & 255u], 1);
            csrc[slot] = (int)(p >> 8);
        }
    } else {
        int bb = blockIdx.x - NB;
        int g = bb >> 2;
        int part = bb & 3;
        int lo = 0, hi = NN;
        while (lo < hi) { int m = (lo + hi) >> 1; if (batch[m] < g) lo = m + 1; else hi = m; }
        int s = lo;
        lo = 0; hi = NN;
        while (lo < hi) { int m = (lo + hi) >> 1; if (batch[m] < g + 1) lo = m + 1; else hi = m; }
        int e = lo;

        __shared__ float sh[16][136];
        int ns = (int)(threadIdx.x >> 4);
        int L  = (int)(threadIdx.x & 15);
        int c8 = L << 3;
        float acc[8] = {};
        for (int v = s + part + ns * 4; v < e; v += 64) {
            ushort8_t t = *(const ushort8_t*)(h + (size_t)(v >> 4) * 2048 + L * 128 + (v & 15) * 8);
#pragma unroll
            for (int j = 0; j < 8; ++j) acc[j] += bf2f(t[j]);
        }
#pragma unroll
        for (int j = 0; j < 8; ++j) sh[ns][c8 + j] = acc[j];
        __syncthreads();
        if (threadIdx.x < 128) {
            int c = (int)threadIdx.x;
            float sum = 0.f;
#pragma unroll
            for (int k = 0; k < 16; ++k) sum += sh[k][c];
            unsafeAtomicAdd(&reps[(size_t)g * 128 + c], sum * invcnt[g]);
        }
    }
}

// ---------------- standalone GCN gemm (MODE 1, LDS-repacked stores) ----------------
__global__ __launch_bounds__(256) void gemm_gcn(const ushort_t* __restrict__ a_bf,
                                                const ushort_t* __restrict__ wt_hi,
                                                const ushort_t* __restrict__ wt_lo,
                                                const float* __restrict__ dinv,
                                                ushort_t* __restrict__ hwb) {
    __shared__ ushort_t lds[4][32][130];
    gemm_body<0, 1>(blockIdx.x, threadIdx.x, nullptr, a_bf, wt_hi, wt_lo,
                    nullptr, dinv, hwb, NN, lds[threadIdx.x >> 6]);
}

// ---------------- gather + fused readout (round-13 version) ----------------
__global__ __launch_bounds__(256) void gather_agg(const int* __restrict__ rp,
                                                  const int* __restrict__ csrc,
                                                  const float* __restrict__ dinv,
                                                  const ushort_t* __restrict__ hwb,
                                                  const float* __restrict__ bias,
                                                  const int* __restrict__ batch,
                                                  const float* __restrict__ invcnt,
                                                  float* __restrict__ reps,
                                                  ushort_t* __restrict__ h_out) {
    __shared__ float sh[16][136];
    __shared__ int gid[16];
    const int v0 = blockIdx.x * 16;
    const int ns = (int)(threadIdx.x >> 4);
    int v = v0 + ns;
    int L = (int)(threadIdx.x & 15);
    int c8 = L << 3;
    if (threadIdx.x < 16) {
        int bidx = v0 + (int)threadIdx.x;
        if (bidx > NN - 1) bidx = NN - 1;
        gid[threadIdx.x] = batch[bidx];
    }

    float acc[8] = {};
    if (v < NN) {
        int s = rp[v], e = rp[v + 1];
        int i = s;
        for (; i + 16 <= e; i += 16) {
            int u[16];
#pragma unroll
            for (int k = 0; k < 16; ++k) u[k] = csrc[i + k];
            ushort8_t r[16];
#pragma unroll
            for (int k = 0; k < 16; ++k) r[k] = *(const ushort8_t*)(hwb + (size_t)u[k] * 128 + c8);
#pragma unroll
            for (int k = 0; k < 16; ++k)
#pragma unroll
                for (int j = 0; j < 8; ++j) acc[j] += bf2f(r[k][j]);
        }
        for (; i + 8 <= e; i += 8) {
            int u[8];
#pragma unroll
            for (int k = 0; k < 8; ++k) u[k] = csrc[i + k];
            ushort8_t r[8];
#pragma unroll
            for (int k = 0; k < 8; ++k) r[k] = *(const ushort8_t*)(hwb + (size_t)u[k] * 128 + c8);
#pragma unroll
            for (int k = 0; k < 8; ++k)
#pragma unroll
                for (int j = 0; j < 8; ++j) acc[j] += bf2f(r[k][j]);
        }
        for (; i < e; ++i) {
            int u = csrc[i];
            ushort8_t r0 = *(const ushort8_t*)(hwb + (size_t)u * 128 + c8);
#pragma unroll
            for (int j = 0; j < 8; ++j) acc[j] += bf2f(r0[j]);
        }

        float di = dinv[v];
        ushort8_t sv = *(const ushort8_t*)(hwb + (size_t)v * 128 + c8);
        ushort8_t o;
#pragma unroll
        for (int j = 0; j < 8; ++j) {
            float t = di * (acc[j] + bf2f(sv[j])) + bias[c8 + j];
            t = t > 0.f ? t : expf(t) - 1.f;
            acc[j] = t;
            o[j] = f2bf(t);
        }
        *(ushort8_t*)(h_out + (size_t)blockIdx.x * 2048 + L * 128 + ns * 8) = o;
    } else {
#pragma unroll
        for (int j = 0; j < 8; ++j) acc[j] = 0.f;
    }

#pragma unroll
    for (int j = 0; j < 8; ++j) sh[ns][c8 + j] = acc[j];
    __syncthreads();
    if (threadIdx.x < 128) {
        int c = (int)threadIdx.x;
        int nvalid = NN - v0;
        if (nvalid > 16) nvalid = 16;
        float run = sh[0][c];
        int cg = gid[0];
        for (int k = 1; k < nvalid; ++k) {
            int g2 = gid[k];
            if (g2 != cg) {
                unsafeAtomicAdd(&reps[(size_t)cg * 128 + c], run * invcnt[cg]);
                run = 0.f;
                cg = g2;
            }
            run += sh[k][c];
        }
        unsafeAtomicAdd(&reps[(size_t)cg * 128 + c], run * invcnt[cg]);
    }
}

// ---------------- fused head ----------------
__global__ __launch_bounds__(128) void head_fused(const float* __restrict__ reps,
                                                  const float* __restrict__ wout,
                                                  const float* __restrict__ bout,
                                                  const float* __restrict__ cw,
                                                  const float* __restrict__ cb,
                                                  float* __restrict__ out) {
    __shared__ float rrow[128];
    __shared__ float gg[128];
    __shared__ float lg[10];
    int t = threadIdx.x;
    int g = blockIdx.x;
    rrow[t] = reps[(size_t)g * 128 + t];
    __syncthreads();
    float a = bout[t];
    for (int k = 0; k < 128; ++k) a = fmaf(rrow[k], wout[k * 128 + t], a);
    a = a > 0.f ? a : expf(a) - 1.f;
    gg[t] = a;
    __syncthreads();
    if (t < 10) {
        float s = cb[t];
        for (int k = 0; k < 128; ++k) s = fmaf(gg[k], cw[k * 10 + t], s);
        lg[t] = s;
    }
    __syncthreads();
    if (t == 0) {
        float m = lg[0];
#pragma unroll
        for (int j = 1; j < 10; ++j) m = fmaxf(m, lg[j]);
        float se = 0.f;
#pragma unroll
        for (int j = 0; j < 10; ++j) se += expf(lg[j] - m);
        float L = logf(se);
#pragma unroll
        for (int j = 0; j < 10; ++j) out[(size_t)g * 10 + j] = lg[j] - m - L;
    }
}

extern "C" void kernel_launch(void* const* d_in, const int* in_sizes, int n_in,
                              void* d_out, int out_size, void* d_ws, size_t ws_size,
                              hipStream_t stream) {
    const float* x        = (const float*)d_in[0];
    const float* lin1_w   = (const float*)d_in[1];
    const float* lin1_b   = (const float*)d_in[2];
    const float* gcn_w    = (const float*)d_in[3];
    const float* gcn_b    = (const float*)d_in[4];
    const float* lin_out_w= (const float*)d_in[5];
    const float* lin_out_b= (const float*)d_in[6];
    const float* cls_w    = (const float*)d_in[7];
    const float* cls_b    = (const float*)d_in[8];
    const int*   ei       = (const int*)d_in[9];
    const int*   batch    = (const int*)d_in[10];
    float* out = (float*)d_out;

    const int* erow = ei;
    const int* ecol = ei + NE;

    ushort_t* h     = (ushort_t*)d_ws;                     // NN*128 bf16 (PERM)
    ushort_t* hwb   = h + (size_t)NN * 128;                // NN*128 bf16 (row-major)
    float*    dinv  = (float*)(hwb + (size_t)NN * 128);    // NN
    float*    reps  = dinv + NN;                           // NG*128
    float*    invcnt= reps + (size_t)NG * 128;             // NG
    int*      rp    = (int*)(invcnt + NG);                 // NN+1
    int*      csrc  = rp + NN + 1;                         // NE
    int*      brp   = csrc + NE;                           // NB+1
    int*      bcount= brp + NB + 1;                        // NPARTB*NB
    int*      basew = bcount + NPARTB * NB;                // NPARTB*NB
    ushort_t* wt_hi = (ushort_t*)(basew + NPARTB * NB);    // 4*16384
    ushort_t* wt_lo = wt_hi + 4 * 16384;                   // 4*16384
    unsigned int* pairs = (unsigned int*)(wt_lo + 4 * 16384);  // NE

    hist_prepw<<<NPARTB + 32, 256, 0, stream>>>(ecol, bcount, lin1_w, gcn_w, wt_hi, wt_lo);
    scan_bases<<<1, NB, 0, stream>>>(bcount, basew, brp, rp, batch, invcnt, reps);
    part_gemm1<<<NPARTB + GEMM_GRID, 256, 0, stream>>>(erow, ecol, brp, basew, pairs,
                                                       x, wt_hi, wt_lo, lin1_b, h);
    fill_readout0<<<NB + NG * 4, 256, 0, stream>>>(pairs, brp, rp, dinv, csrc,
                                                   h, batch, invcnt, reps);

    for (int i = 0; i < 3; ++i) {
        gemm_gcn<<<GEMM_GRID, 256, 0, stream>>>(h, wt_hi + (size_t)(i + 1) * 16384,
                                                wt_lo + (size_t)(i + 1) * 16384,
                                                dinv, hwb);
        gather_agg<<<(NN + 15) / 16, 256, 0, stream>>>(rp, csrc, dinv, hwb,
                                                       gcn_b + (size_t)i * 128,
                                                       batch, invcnt, reps, h);
    }

    head_fused<<<NG, 128, 0, stream>>>(reps, lin_out_w, lin_out_b, cls_w, cls_b, out);
}